// Round 5
// baseline (163.873 us; speedup 1.0000x reference)
//
#include <hip/hip_runtime.h>
#include <math.h>

// Match x86 reference LAPACK (no FMA contraction anywhere in the emulation).
#pragma clang fp contract(off)

#define NIT 35      // provable: prob=min(...,0.99)<=0.99 => k<=35.49 => reason<=35 => no update past it=34
#define BB  32
#define NPTS 32768

// ---------------- LAPACK helpers (fp32, faithful) ----------------

__device__ __forceinline__ float slapy2f(float x, float y){
  float xa = fabsf(x), ya = fabsf(y);
  float w = fmaxf(xa, ya), z = fminf(xa, ya);
  if (z == 0.0f) return w;
  float q = z / w;
  return w * sqrtf(1.0f + q*q);
}

// LAPACK >= 3.10 slartg (modern OpenBLAS as shipped with numpy/scipy).
__device__ __forceinline__ void slartgf(float f, float g, float* cs, float* sn, float* r){
  if (g == 0.0f){ *cs = 1.0f; *sn = 0.0f; *r = f; return; }
  if (f == 0.0f){ *cs = 0.0f; *sn = copysignf(1.0f, g); *r = fabsf(g); return; }
  float f1 = fabsf(f);
  float d  = sqrtf(f*f + g*g);
  *cs = f1 / d;
  *r  = copysignf(d, f);
  *sn = g / (*r);
}

__device__ void slaev2f(float a, float b, float c,
                        float* rt1, float* rt2, float* cs1, float* sn1){
  float sm  = a + c;
  float df  = a - c;
  float adf = fabsf(df);
  float tb  = b + b;
  float ab  = fabsf(tb);
  float acmx, acmn;
  if (fabsf(a) > fabsf(c)){ acmx = a; acmn = c; } else { acmx = c; acmn = a; }
  float rt;
  if (adf > ab){ float q = ab/adf; rt = adf*sqrtf(1.0f + q*q); }
  else if (adf < ab){ float q = adf/ab; rt = ab*sqrtf(1.0f + q*q); }
  else rt = ab*sqrtf(2.0f);
  int sgn1;
  if (sm < 0.0f){
    *rt1 = 0.5f*(sm - rt); sgn1 = -1;
    *rt2 = (acmx / *rt1)*acmn - (b / *rt1)*b;
  } else if (sm > 0.0f){
    *rt1 = 0.5f*(sm + rt); sgn1 = 1;
    *rt2 = (acmx / *rt1)*acmn - (b / *rt1)*b;
  } else {
    *rt1 = 0.5f*rt; *rt2 = -0.5f*rt; sgn1 = 1;
  }
  float cs; int sgn2;
  if (df >= 0.0f){ cs = df + rt; sgn2 = 1; } else { cs = df - rt; sgn2 = -1; }
  float acs = fabsf(cs);
  float cs1v, sn1v;
  if (acs > ab){
    float ct = -tb/cs;
    sn1v = 1.0f/sqrtf(1.0f + ct*ct);
    cs1v = ct*sn1v;
  } else {
    if (ab == 0.0f){ cs1v = 1.0f; sn1v = 0.0f; }
    else {
      float tn = -cs/tb;
      cs1v = 1.0f/sqrtf(1.0f + tn*tn);
      sn1v = tn*cs1v;
    }
  }
  if (sgn1 == sgn2){ float t = cs1v; cs1v = -sn1v; sn1v = t; }
  *cs1 = cs1v; *sn1 = sn1v;
}

// ---- register-resident dynamic access (R2-proven text; if-else accessor chains) ----
#define RD_D(i)   ((i)==1?d1:(i)==2?d2:(i)==3?d3:d4)
#define WR_D(i,v) do{ float _v=(v); int _ix=(i); if(_ix==1)d1=_v; else if(_ix==2)d2=_v; else if(_ix==3)d3=_v; else d4=_v; }while(0)
#define RD_E(i)   ((i)==1?e1:(i)==2?e2:(i)==3?e3:e4)
#define WR_E(i,v) do{ float _v=(v); int _ix=(i); if(_ix==1)e1=_v; else if(_ix==2)e2=_v; else if(_ix==3)e3=_v; else e4=_v; }while(0)
#define RD_W(i)   ((i)==1?w1:(i)==2?w2:(i)==3?w3:(i)==4?w4:(i)==5?w5:(i)==6?w6:w7)
#define WR_W(i,v) do{ float _v=(v); int _ix=(i); if(_ix==1)w1=_v; else if(_ix==2)w2=_v; else if(_ix==3)w3=_v; else if(_ix==4)w4=_v; else if(_ix==5)w5=_v; else if(_ix==6)w6=_v; else w7=_v; }while(0)
#define RD_Z(i,j) ((j)==1? z##i##1 : (j)==2? z##i##2 : (j)==3? z##i##3 : z##i##4)
#define WR_Z(i,j,v) do{ float _vv=(v); int _jj=(j); \
  if(_jj==1) z##i##1=_vv; else if(_jj==2) z##i##2=_vv; else if(_jj==3) z##i##3=_vv; else z##i##4=_vv; }while(0)
// rotate columns (jv, jv-1): temp=Z(:,jv); Z(:,jv)=c*temp - s*Z(:,jv-1); Z(:,jv-1)=s*temp + c*Z(:,jv-1)
#define ROTZ_ROW(i,jv,cv,sv) do{ \
  float _t = RD_Z(i,(jv)); float _o = RD_Z(i,(jv)-1); \
  float _nt = (cv)*_t - (sv)*_o; \
  float _no = (sv)*_t + (cv)*_o; \
  WR_Z(i,(jv),_nt); WR_Z(i,(jv)-1,_no); \
}while(0)
#define ROTZ(jv,cv,sv) do{ int _rj=(jv); float _rc=(cv), _rs=(sv); \
  ROTZ_ROW(1,_rj,_rc,_rs); ROTZ_ROW(2,_rj,_rc,_rs); ROTZ_ROW(3,_rj,_rc,_rs); ROTZ_ROW(4,_rj,_rc,_rs); }while(0)

// ---------------- Kernel 1: one (it,b) problem per WAVE, R2-proven eigensolver text ----------------

__global__ void __launch_bounds__(64) models_kernel(const float* __restrict__ data,
                                                    const int* __restrict__ idx,
                                                    float* __restrict__ models,
                                                    int* __restrict__ counts,
                                                    int* __restrict__ ticket){
  const int t = blockIdx.x;              // 0..NIT*BB-1; all 64 lanes compute redundantly
  if (threadIdx.x == 0) counts[t] = 0;   // count_kernel is a later dispatch; stream order safe
  if (threadIdx.x == 0 && t == 0) *ticket = 0;
  const int it = t >> 5;
  const int b  = t & 31;

  // gather 3 samples, aug rows [x,y,z,1]
  float P[3][4];
  const int* ip = &idx[(it*BB + b)*3];
  #pragma unroll
  for (int s=0;s<3;s++){
    int n = ip[s];
    const float* pp = &data[((long)b*NPTS + n)*3];
    P[s][0]=pp[0]; P[s][1]=pp[1]; P[s][2]=pp[2]; P[s][3]=1.0f;
  }
  // A = aug^T aug (sum over s in order 0,1,2; separate rounding)
  float A[5][5];
  #pragma unroll
  for (int i=0;i<4;i++)
    #pragma unroll
    for (int j=0;j<4;j++){
      float acc = P[0][i]*P[0][j];
      acc = acc + P[1][i]*P[1][j];
      acc = acc + P[2][i]*P[2][j];
      A[i+1][j+1] = acc;
    }

  // ssytd2 (UPLO='L', n=4): reference-BLAS op ordering
  float eE[5], tauv[4];
  #pragma unroll
  for (int i=1;i<=3;i++){
    float alpha = A[i+1][i];
    float ssq = 0.0f;
    #pragma unroll
    for (int k=i+2;k<=4;k++) ssq = ssq + A[k][i]*A[k][i];
    float xnorm = sqrtf(ssq);
    float taui;
    if (xnorm == 0.0f){
      taui = 0.0f;
    } else {
      float beta = -copysignf(slapy2f(alpha, xnorm), alpha);
      taui = (beta - alpha)/beta;
      float sc = 1.0f/(alpha - beta);
      #pragma unroll
      for (int k=i+2;k<=4;k++) A[k][i] = A[k][i]*sc;
      alpha = beta;
    }
    eE[i] = alpha;
    if (taui != 0.0f){
      A[i+1][i] = 1.0f;
      float w[5];
      #pragma unroll
      for (int r=i+1;r<=4;r++) w[r] = 0.0f;
      // ssymv('L'): w = taui * Asub * v
      #pragma unroll
      for (int j=i+1;j<=4;j++){
        float temp1 = taui*A[j][i];
        float temp2 = 0.0f;
        w[j] = w[j] + temp1*A[j][j];
        #pragma unroll
        for (int r=j+1;r<=4;r++){
          w[r] = w[r] + temp1*A[r][j];
          temp2 = temp2 + A[r][j]*A[r][i];
        }
        w[j] = w[j] + taui*temp2;
      }
      float dot = 0.0f;
      #pragma unroll
      for (int r=i+1;r<=4;r++) dot = dot + w[r]*A[r][i];
      float alpha2 = (-0.5f*taui)*dot;
      #pragma unroll
      for (int r=i+1;r<=4;r++) w[r] = w[r] + alpha2*A[r][i];
      // ssyr2('L', alpha=-1)
      #pragma unroll
      for (int j=i+1;j<=4;j++){
        float xj = A[j][i], yj = w[j];
        if (xj != 0.0f || yj != 0.0f){
          float temp1 = -yj;
          float temp2 = -xj;
          #pragma unroll
          for (int r=j;r<=4;r++){
            float acc = A[r][j] + A[r][i]*temp1;
            acc = acc + w[r]*temp2;
            A[r][j] = acc;
          }
        }
      }
    }
    tauv[i] = taui;
  }

  // ---------------- ssteqr('I', n=4), all state in registers (R2 text, deferred slasr) ----------------
  float d1=A[1][1], d2=A[2][2], d3=A[3][3], d4=A[4][4];
  float e1=eE[1], e2=eE[2], e3=eE[3], e4=0.0f;
  float w1=0,w2=0,w3=0,w4=0,w5=0,w6=0,w7=0;
  float z11=1,z12=0,z13=0,z14=0;
  float z21=0,z22=1,z23=0,z24=0;
  float z31=0,z32=0,z33=1,z34=0;
  float z41=0,z42=0,z43=0,z44=1;
  (void)e4; (void)w7;

  {
    const float eps    = 5.9604645e-08f;
    const float eps2   = eps*eps;
    const float safmin = 1.17549435e-38f;
    const int nmaxit = 4*30;
    int jtot = 0;

    int l1 = 1;
    while (l1 <= 4){
      if (l1 > 1) WR_E(l1-1, 0.0f);
      int m = 4;
      for (int mm = l1; mm <= 3; mm++){
        float tst = fabsf(RD_E(mm));
        if (tst == 0.0f){ m = mm; break; }
        if (tst <= (sqrtf(fabsf(RD_D(mm))) * sqrtf(fabsf(RD_D(mm+1)))) * eps){
          WR_E(mm, 0.0f); m = mm; break;
        }
      }
      int l = l1, lsv = l, lend = m, lendsv = lend;
      l1 = m + 1;
      if (lend == l) continue;

      float anorm = 0.0f;
      for (int i=l;i<=lend;i++)   anorm = fmaxf(anorm, fabsf(RD_D(i)));
      for (int i=l;i<=lend-1;i++) anorm = fmaxf(anorm, fabsf(RD_E(i)));
      if (anorm == 0.0f) continue;

      if (fabsf(RD_D(lend)) < fabsf(RD_D(l))){ lend = lsv; l = lendsv; }

      if (lend > l){
        // ---------------- QL iteration ----------------
        for(;;){
          int m2 = lend;
          if (l != lend){
            for (int mm = l; mm <= lend-1; mm++){
              float tst = RD_E(mm)*RD_E(mm);
              if (tst <= (eps2*fabsf(RD_D(mm)))*fabsf(RD_D(mm+1)) + safmin){ m2 = mm; break; }
            }
          }
          if (m2 < lend) WR_E(m2, 0.0f);
          float p = RD_D(l);
          if (m2 == l){
            WR_D(l, p); l = l + 1;
            if (l <= lend) continue;
            break;
          }
          if (m2 == l+1){
            float rt1, rt2, c1, s1;
            slaev2f(RD_D(l), RD_E(l), RD_D(l+1), &rt1, &rt2, &c1, &s1);
            WR_W(l, c1); WR_W(3+l, s1);
            ROTZ(l+1, c1, s1);
            WR_D(l, rt1); WR_D(l+1, rt2); WR_E(l, 0.0f);
            l = l + 2;
            if (l <= lend) continue;
            break;
          }
          if (jtot == nmaxit) break;
          jtot++;
          float g = (RD_D(l+1) - p) / (2.0f*RD_E(l));
          float r = slapy2f(g, 1.0f);
          g = RD_D(m2) - p + (RD_E(l) / (g + copysignf(r, g)));
          float s = 1.0f, c = 1.0f;
          p = 0.0f;
          for (int i = m2-1; i >= l; i--){
            float f  = s*RD_E(i);
            float bq = c*RD_E(i);
            slartgf(g, f, &c, &s, &r);
            if (i != m2-1) WR_E(i+1, r);
            g = RD_D(i+1) - p;
            r = (RD_D(i) - g)*s + (2.0f*c)*bq;
            p = s*r;
            WR_D(i+1, g + p);
            g = c*r - bq;
            WR_W(i, c);
            WR_W(3+i, -s);
          }
          int mmn = m2 - l + 1;    // slasr('R','V','B')
          for (int j = mmn-1; j >= 1; j--){
            float ct = RD_W(l+j-1), sx = RD_W(3+l+j-1);
            if (ct != 1.0f || sx != 0.0f) ROTZ(l+j, ct, sx);
          }
          WR_D(l, RD_D(l) - p);
          WR_E(l, g);
        }
      } else {
        // ---------------- QR iteration ----------------
        for(;;){
          int m2 = lend;
          if (l != lend){
            for (int mm = l; mm >= lend+1; mm--){
              float tst = RD_E(mm-1)*RD_E(mm-1);
              if (tst <= (eps2*fabsf(RD_D(mm)))*fabsf(RD_D(mm-1)) + safmin){ m2 = mm; break; }
            }
          }
          if (m2 > lend) WR_E(m2-1, 0.0f);
          float p = RD_D(l);
          if (m2 == l){
            WR_D(l, p); l = l - 1;
            if (l >= lend) continue;
            break;
          }
          if (m2 == l-1){
            float rt1, rt2, c1, s1;
            slaev2f(RD_D(l-1), RD_E(l-1), RD_D(l), &rt1, &rt2, &c1, &s1);
            WR_W(m2, c1); WR_W(3+m2, s1);
            ROTZ(l, c1, s1);
            WR_D(l-1, rt1); WR_D(l, rt2); WR_E(l-1, 0.0f);
            l = l - 2;
            if (l >= lend) continue;
            break;
          }
          if (jtot == nmaxit) break;
          jtot++;
          float g = (RD_D(l-1) - p) / (2.0f*RD_E(l-1));
          float r = slapy2f(g, 1.0f);
          g = RD_D(m2) - p + (RD_E(l-1) / (g + copysignf(r, g)));
          float s = 1.0f, c = 1.0f;
          p = 0.0f;
          for (int i = m2; i <= l-1; i++){
            float f  = s*RD_E(i);
            float bq = c*RD_E(i);
            slartgf(g, f, &c, &s, &r);
            if (i != m2) WR_E(i-1, r);
            g = RD_D(i) - p;
            r = (RD_D(i+1) - g)*s + (2.0f*c)*bq;
            p = s*r;
            WR_D(i, g + p);
            g = c*r - bq;
            WR_W(i, c);
            WR_W(3+i, s);
          }
          int mmn = l - m2 + 1;    // slasr('R','V','F')
          for (int j = 1; j <= mmn-1; j++){
            float ct = RD_W(m2+j-1), sx = RD_W(3+m2+j-1);
            if (ct != 1.0f || sx != 0.0f) ROTZ(m2+j, ct, sx);
          }
          WR_D(l, RD_D(l) - p);
          WR_E(l-1, g);
        }
      }
      if (jtot >= nmaxit) break;
    }
  }

  // argmin eigenvalue (first minimum — matches ssteqr selection-sort rank-0 pick)
  int kbest = 1;
  float dmin = d1;
  if (d2 < dmin){ dmin = d2; kbest = 2; }
  if (d3 < dmin){ dmin = d3; kbest = 3; }
  if (d4 < dmin){ dmin = d4; kbest = 4; }
  float zc1 = RD_Z(1,kbest);
  float zc2 = RD_Z(2,kbest);
  float zc3 = RD_Z(3,kbest);
  float zc4 = RD_Z(4,kbest);

  // sormtr: apply Q = H1*H2 (H2 first, then H1); H3 has tau=0
  {
    float v2 = A[4][2];
    float sum = zc3 + v2*zc4;
    float tt = tauv[2]*sum;
    zc3 = zc3 - tt;
    zc4 = zc4 - tt*v2;
  }
  {
    float va = A[3][1], vb = A[4][1];
    float sum = zc2 + va*zc3;
    sum = sum + vb*zc4;
    float tt = tauv[1]*sum;
    zc2 = zc2 - tt;
    zc3 = zc3 - tt*va;
    zc4 = zc4 - tt*vb;
  }

  // reference post-process: normalize by ||(a,b,c)||, sign-fix abc only
  float n2 = zc1*zc1;
  n2 = n2 + zc2*zc2;
  n2 = n2 + zc3*zc3;
  float nrm = sqrtf(n2);
  float a0 = zc1/nrm;
  float b0 = zc2/nrm;
  float c0 = zc3/nrm;
  float d0 = zc4/nrm;
  float sg = (b0 < 0.0f) ? -1.0f : 1.0f;
  a0 = a0*sg; b0 = b0*sg; c0 = c0*sg;

  if (threadIdx.x == 0){
    float* mp = &models[(size_t)t*4];
    mp[0]=a0; mp[1]=b0; mp[2]=c0; mp[3]=d0;
  }
}

// ---------------- Kernel 2: inlier counting + last-block scan (fused) ----------------
// Scan arithmetic is a verbatim copy of the R4 scan_kernel (order-preserved loops),
// run by the last count block (ticket pattern, device-scope atomics).

__global__ void __launch_bounds__(256) count_kernel(const float* __restrict__ data,
                                                    const float* __restrict__ models,
                                                    int* __restrict__ counts,
                                                    int* __restrict__ ticket,
                                                    float* __restrict__ out){
  __shared__ float4 smodel[NIT];
  __shared__ int   slast;
  __shared__ int   icarr[NIT*BB];
  __shared__ int   pmarr[NIT*BB];
  __shared__ float karr[NIT*BB];
  __shared__ int   sdone[NIT];
  __shared__ int   sistop;

  const int b = blockIdx.y;
  const int chunk = blockIdx.x;
  const int t = threadIdx.x;
  if (t < NIT) smodel[t] = ((const float4*)models)[t*BB + b];
  __syncthreads();

  float x[8], y[8], z[8];
  const long base = (long)b*NPTS + (long)chunk*2048;
  #pragma unroll
  for (int k=0;k<8;k++){
    const float* pp = &data[(base + (long)k*256 + t)*3];
    x[k]=pp[0]; y[k]=pp[1]; z[k]=pp[2];
  }
  const int lane = t & 63;
  for (int m=0;m<NIT;m++){
    float4 md = smodel[m];
    int cnt = 0;
    #pragma unroll
    for (int k=0;k<8;k++){
      // numpy einsum order, separate rounding (no FMA): ((a*x + b*y) + c*z) + d
      float s = __fmul_rn(md.x, x[k]);
      s = __fadd_rn(s, __fmul_rn(md.y, y[k]));
      s = __fadd_rn(s, __fmul_rn(md.z, z[k]));
      s = __fadd_rn(s, md.w);
      unsigned long long msk = __ballot(fabsf(s) < 0.05f);
      cnt += (int)__popcll(msk);
    }
    if (lane == 0) atomicAdd(&counts[m*BB + b], cnt);
  }

  // ---- last-block detection ----
  __threadfence();
  if (t == 0){
    int old = __hip_atomic_fetch_add(ticket, 1, __ATOMIC_ACQ_REL, __HIP_MEMORY_SCOPE_AGENT);
    slast = (old == 16*BB - 1) ? 1 : 0;
  }
  __syncthreads();
  if (!slast) return;

  // ---- scan (verbatim R4 scan_kernel arithmetic; lanes 0..63 of this block) ----
  if (t < 64){
    for (int tt = t; tt < NIT*BB; tt += 64)
      icarr[tt] = __hip_atomic_load(&counts[tt], __ATOMIC_RELAXED, __HIP_MEMORY_SCOPE_AGENT);
  }
  __syncthreads();
  if (t < BB){
    int pm = 0;
    for (int it=0; it<NIT; it++){
      int ic = icarr[it*BB + t];
      pm = (ic > pm) ? ic : pm;
      pmarr[it*BB + t] = pm;
    }
  }
  __syncthreads();
  if (t < 64){
    for (int tt = t; tt < NIT*BB; tt += 64){
      float p = (float)pmarr[tt] / 32768.0f;
      float p3 = (p*p)*p;
      float prob = fminf(1.0f - p3, 0.99f);
      karr[tt] = -0.35667494393873245f / (logf(prob) + 1e-10f);
    }
  }
  __syncthreads();
  if (t < NIT){
    float kmax = karr[t*BB];
    for (int bb=1;bb<BB;bb++) kmax = fmaxf(kmax, karr[t*BB + bb]);
    int reason = (int)kmax;            // astype(int32): trunc toward zero
    if (reason > 100) reason = 100;
    sdone[t] = ((t+1) >= reason) ? 1 : 0;
  }
  __syncthreads();
  if (t == 0){
    int is = NIT-1;                    // guaranteed hit at it<=34 (reason<=35)
    for (int it=0; it<NIT; it++){ if (sdone[it]){ is = it; break; } }
    sistop = is;
  }
  __syncthreads();
  if (t < BB){
    const int istop = sistop;
    int best = 0, bit = -1;
    for (int it=0; it<=istop; it++){
      int ic = icarr[it*BB + t];
      if (ic > best){ best = ic; bit = it; }
    }
    float4 m = make_float4(0.0f,0.0f,0.0f,0.0f);
    if (bit >= 0) m = ((const float4*)models)[bit*BB + t];
    ((float4*)out)[t] = m;
  }
}

// ---------------- launch ----------------

extern "C" void kernel_launch(void* const* d_in, const int* in_sizes, int n_in,
                              void* d_out, int out_size, void* d_ws, size_t ws_size,
                              hipStream_t stream){
  const float* data = (const float*)d_in[0];
  const int*   idx  = (const int*)d_in[1];
  float* out = (float*)d_out;
  float* models = (float*)d_ws;                                          // NIT*32*4 floats
  int*   counts = (int*)((char*)d_ws + (size_t)NIT*BB*4*sizeof(float));  // NIT*32 ints
  int*   ticket = counts + NIT*BB;                                       // 1 int

  models_kernel<<<NIT*BB, 64, 0, stream>>>(data, idx, models, counts, ticket);
  count_kernel<<<dim3(16, BB), 256, 0, stream>>>(data, models, counts, ticket, out);
}

// Round 6
// 130.443 us; speedup vs baseline: 1.2563x; 1.2563x over previous
//
#include <hip/hip_runtime.h>
#include <math.h>

// Match x86 reference LAPACK (no FMA contraction anywhere in the emulation).
#pragma clang fp contract(off)

#define NIT 35      // provable: prob=min(...,0.99)<=0.99 => k<=35.49 => reason<=35 => no update past it=34
#define BB  32
#define NPTS 32768

// ---------------- LAPACK helpers (fp32, faithful) ----------------

__device__ __forceinline__ float slapy2f(float x, float y){
  float xa = fabsf(x), ya = fabsf(y);
  float w = fmaxf(xa, ya), z = fminf(xa, ya);
  if (z == 0.0f) return w;
  float q = z / w;
  return w * sqrtf(1.0f + q*q);
}

// LAPACK >= 3.10 slartg (modern OpenBLAS as shipped with numpy/scipy).
__device__ __forceinline__ void slartgf(float f, float g, float* cs, float* sn, float* r){
  if (g == 0.0f){ *cs = 1.0f; *sn = 0.0f; *r = f; return; }
  if (f == 0.0f){ *cs = 0.0f; *sn = copysignf(1.0f, g); *r = fabsf(g); return; }
  float f1 = fabsf(f);
  float d  = sqrtf(f*f + g*g);
  *cs = f1 / d;
  *r  = copysignf(d, f);
  *sn = g / (*r);
}

__device__ void slaev2f(float a, float b, float c,
                        float* rt1, float* rt2, float* cs1, float* sn1){
  float sm  = a + c;
  float df  = a - c;
  float adf = fabsf(df);
  float tb  = b + b;
  float ab  = fabsf(tb);
  float acmx, acmn;
  if (fabsf(a) > fabsf(c)){ acmx = a; acmn = c; } else { acmx = c; acmn = a; }
  float rt;
  if (adf > ab){ float q = ab/adf; rt = adf*sqrtf(1.0f + q*q); }
  else if (adf < ab){ float q = adf/ab; rt = ab*sqrtf(1.0f + q*q); }
  else rt = ab*sqrtf(2.0f);
  int sgn1;
  if (sm < 0.0f){
    *rt1 = 0.5f*(sm - rt); sgn1 = -1;
    *rt2 = (acmx / *rt1)*acmn - (b / *rt1)*b;
  } else if (sm > 0.0f){
    *rt1 = 0.5f*(sm + rt); sgn1 = 1;
    *rt2 = (acmx / *rt1)*acmn - (b / *rt1)*b;
  } else {
    *rt1 = 0.5f*rt; *rt2 = -0.5f*rt; sgn1 = 1;
  }
  float cs; int sgn2;
  if (df >= 0.0f){ cs = df + rt; sgn2 = 1; } else { cs = df - rt; sgn2 = -1; }
  float acs = fabsf(cs);
  float cs1v, sn1v;
  if (acs > ab){
    float ct = -tb/cs;
    sn1v = 1.0f/sqrtf(1.0f + ct*ct);
    cs1v = ct*sn1v;
  } else {
    if (ab == 0.0f){ cs1v = 1.0f; sn1v = 0.0f; }
    else {
      float tn = -cs/tb;
      cs1v = 1.0f/sqrtf(1.0f + tn*tn);
      sn1v = tn*cs1v;
    }
  }
  if (sgn1 == sgn2){ float t = cs1v; cs1v = -sn1v; sn1v = t; }
  *cs1 = cs1v; *sn1 = sn1v;
}

// ---- register-resident dynamic access (R2-proven text; if-else accessor chains) ----
#define RD_D(i)   ((i)==1?d1:(i)==2?d2:(i)==3?d3:d4)
#define WR_D(i,v) do{ float _v=(v); int _ix=(i); if(_ix==1)d1=_v; else if(_ix==2)d2=_v; else if(_ix==3)d3=_v; else d4=_v; }while(0)
#define RD_E(i)   ((i)==1?e1:(i)==2?e2:(i)==3?e3:e4)
#define WR_E(i,v) do{ float _v=(v); int _ix=(i); if(_ix==1)e1=_v; else if(_ix==2)e2=_v; else if(_ix==3)e3=_v; else e4=_v; }while(0)
#define RD_W(i)   ((i)==1?w1:(i)==2?w2:(i)==3?w3:(i)==4?w4:(i)==5?w5:(i)==6?w6:w7)
#define WR_W(i,v) do{ float _v=(v); int _ix=(i); if(_ix==1)w1=_v; else if(_ix==2)w2=_v; else if(_ix==3)w3=_v; else if(_ix==4)w4=_v; else if(_ix==5)w5=_v; else if(_ix==6)w6=_v; else w7=_v; }while(0)
#define RD_Z(i,j) ((j)==1? z##i##1 : (j)==2? z##i##2 : (j)==3? z##i##3 : z##i##4)
#define WR_Z(i,j,v) do{ float _vv=(v); int _jj=(j); \
  if(_jj==1) z##i##1=_vv; else if(_jj==2) z##i##2=_vv; else if(_jj==3) z##i##3=_vv; else z##i##4=_vv; }while(0)
// rotate columns (jv, jv-1): temp=Z(:,jv); Z(:,jv)=c*temp - s*Z(:,jv-1); Z(:,jv-1)=s*temp + c*Z(:,jv-1)
#define ROTZ_ROW(i,jv,cv,sv) do{ \
  float _t = RD_Z(i,(jv)); float _o = RD_Z(i,(jv)-1); \
  float _nt = (cv)*_t - (sv)*_o; \
  float _no = (sv)*_t + (cv)*_o; \
  WR_Z(i,(jv),_nt); WR_Z(i,(jv)-1,_no); \
}while(0)
#define ROTZ(jv,cv,sv) do{ int _rj=(jv); float _rc=(cv), _rs=(sv); \
  ROTZ_ROW(1,_rj,_rc,_rs); ROTZ_ROW(2,_rj,_rc,_rs); ROTZ_ROW(3,_rj,_rc,_rs); ROTZ_ROW(4,_rj,_rc,_rs); }while(0)

// ---------------- Kernel 1: one (it,b) problem per WAVE, R2-proven eigensolver text ----------------

__global__ void __launch_bounds__(64) models_kernel(const float* __restrict__ data,
                                                    const int* __restrict__ idx,
                                                    float* __restrict__ models,
                                                    int* __restrict__ counts){
  const int t = blockIdx.x;              // 0..NIT*BB-1; all 64 lanes compute redundantly
  if (threadIdx.x == 0) counts[t] = 0;   // count_kernel is a later dispatch; stream order safe
  const int it = t >> 5;
  const int b  = t & 31;

  // gather 3 samples, aug rows [x,y,z,1]
  float P[3][4];
  const int* ip = &idx[(it*BB + b)*3];
  #pragma unroll
  for (int s=0;s<3;s++){
    int n = ip[s];
    const float* pp = &data[((long)b*NPTS + n)*3];
    P[s][0]=pp[0]; P[s][1]=pp[1]; P[s][2]=pp[2]; P[s][3]=1.0f;
  }
  // A = aug^T aug (sum over s in order 0,1,2; separate rounding)
  float A[5][5];
  #pragma unroll
  for (int i=0;i<4;i++)
    #pragma unroll
    for (int j=0;j<4;j++){
      float acc = P[0][i]*P[0][j];
      acc = acc + P[1][i]*P[1][j];
      acc = acc + P[2][i]*P[2][j];
      A[i+1][j+1] = acc;
    }

  // ssytd2 (UPLO='L', n=4): reference-BLAS op ordering
  float eE[5], tauv[4];
  #pragma unroll
  for (int i=1;i<=3;i++){
    float alpha = A[i+1][i];
    float ssq = 0.0f;
    #pragma unroll
    for (int k=i+2;k<=4;k++) ssq = ssq + A[k][i]*A[k][i];
    float xnorm = sqrtf(ssq);
    float taui;
    if (xnorm == 0.0f){
      taui = 0.0f;
    } else {
      float beta = -copysignf(slapy2f(alpha, xnorm), alpha);
      taui = (beta - alpha)/beta;
      float sc = 1.0f/(alpha - beta);
      #pragma unroll
      for (int k=i+2;k<=4;k++) A[k][i] = A[k][i]*sc;
      alpha = beta;
    }
    eE[i] = alpha;
    if (taui != 0.0f){
      A[i+1][i] = 1.0f;
      float w[5];
      #pragma unroll
      for (int r=i+1;r<=4;r++) w[r] = 0.0f;
      // ssymv('L'): w = taui * Asub * v
      #pragma unroll
      for (int j=i+1;j<=4;j++){
        float temp1 = taui*A[j][i];
        float temp2 = 0.0f;
        w[j] = w[j] + temp1*A[j][j];
        #pragma unroll
        for (int r=j+1;r<=4;r++){
          w[r] = w[r] + temp1*A[r][j];
          temp2 = temp2 + A[r][j]*A[r][i];
        }
        w[j] = w[j] + taui*temp2;
      }
      float dot = 0.0f;
      #pragma unroll
      for (int r=i+1;r<=4;r++) dot = dot + w[r]*A[r][i];
      float alpha2 = (-0.5f*taui)*dot;
      #pragma unroll
      for (int r=i+1;r<=4;r++) w[r] = w[r] + alpha2*A[r][i];
      // ssyr2('L', alpha=-1)
      #pragma unroll
      for (int j=i+1;j<=4;j++){
        float xj = A[j][i], yj = w[j];
        if (xj != 0.0f || yj != 0.0f){
          float temp1 = -yj;
          float temp2 = -xj;
          #pragma unroll
          for (int r=j;r<=4;r++){
            float acc = A[r][j] + A[r][i]*temp1;
            acc = acc + w[r]*temp2;
            A[r][j] = acc;
          }
        }
      }
    }
    tauv[i] = taui;
  }

  // ---------------- ssteqr('I', n=4), all state in registers (R2 text, deferred slasr) ----------------
  float d1=A[1][1], d2=A[2][2], d3=A[3][3], d4=A[4][4];
  float e1=eE[1], e2=eE[2], e3=eE[3], e4=0.0f;
  float w1=0,w2=0,w3=0,w4=0,w5=0,w6=0,w7=0;
  float z11=1,z12=0,z13=0,z14=0;
  float z21=0,z22=1,z23=0,z24=0;
  float z31=0,z32=0,z33=1,z34=0;
  float z41=0,z42=0,z43=0,z44=1;
  (void)e4; (void)w7;

  {
    const float eps    = 5.9604645e-08f;
    const float eps2   = eps*eps;
    const float safmin = 1.17549435e-38f;
    const int nmaxit = 4*30;
    int jtot = 0;

    int l1 = 1;
    while (l1 <= 4){
      if (l1 > 1) WR_E(l1-1, 0.0f);
      int m = 4;
      for (int mm = l1; mm <= 3; mm++){
        float tst = fabsf(RD_E(mm));
        if (tst == 0.0f){ m = mm; break; }
        if (tst <= (sqrtf(fabsf(RD_D(mm))) * sqrtf(fabsf(RD_D(mm+1)))) * eps){
          WR_E(mm, 0.0f); m = mm; break;
        }
      }
      int l = l1, lsv = l, lend = m, lendsv = lend;
      l1 = m + 1;
      if (lend == l) continue;

      float anorm = 0.0f;
      for (int i=l;i<=lend;i++)   anorm = fmaxf(anorm, fabsf(RD_D(i)));
      for (int i=l;i<=lend-1;i++) anorm = fmaxf(anorm, fabsf(RD_E(i)));
      if (anorm == 0.0f) continue;

      if (fabsf(RD_D(lend)) < fabsf(RD_D(l))){ lend = lsv; l = lendsv; }

      if (lend > l){
        // ---------------- QL iteration ----------------
        for(;;){
          int m2 = lend;
          if (l != lend){
            for (int mm = l; mm <= lend-1; mm++){
              float tst = RD_E(mm)*RD_E(mm);
              if (tst <= (eps2*fabsf(RD_D(mm)))*fabsf(RD_D(mm+1)) + safmin){ m2 = mm; break; }
            }
          }
          if (m2 < lend) WR_E(m2, 0.0f);
          float p = RD_D(l);
          if (m2 == l){
            WR_D(l, p); l = l + 1;
            if (l <= lend) continue;
            break;
          }
          if (m2 == l+1){
            float rt1, rt2, c1, s1;
            slaev2f(RD_D(l), RD_E(l), RD_D(l+1), &rt1, &rt2, &c1, &s1);
            WR_W(l, c1); WR_W(3+l, s1);
            ROTZ(l+1, c1, s1);
            WR_D(l, rt1); WR_D(l+1, rt2); WR_E(l, 0.0f);
            l = l + 2;
            if (l <= lend) continue;
            break;
          }
          if (jtot == nmaxit) break;
          jtot++;
          float g = (RD_D(l+1) - p) / (2.0f*RD_E(l));
          float r = slapy2f(g, 1.0f);
          g = RD_D(m2) - p + (RD_E(l) / (g + copysignf(r, g)));
          float s = 1.0f, c = 1.0f;
          p = 0.0f;
          for (int i = m2-1; i >= l; i--){
            float f  = s*RD_E(i);
            float bq = c*RD_E(i);
            slartgf(g, f, &c, &s, &r);
            if (i != m2-1) WR_E(i+1, r);
            g = RD_D(i+1) - p;
            r = (RD_D(i) - g)*s + (2.0f*c)*bq;
            p = s*r;
            WR_D(i+1, g + p);
            g = c*r - bq;
            WR_W(i, c);
            WR_W(3+i, -s);
          }
          int mmn = m2 - l + 1;    // slasr('R','V','B')
          for (int j = mmn-1; j >= 1; j--){
            float ct = RD_W(l+j-1), sx = RD_W(3+l+j-1);
            if (ct != 1.0f || sx != 0.0f) ROTZ(l+j, ct, sx);
          }
          WR_D(l, RD_D(l) - p);
          WR_E(l, g);
        }
      } else {
        // ---------------- QR iteration ----------------
        for(;;){
          int m2 = lend;
          if (l != lend){
            for (int mm = l; mm >= lend+1; mm--){
              float tst = RD_E(mm-1)*RD_E(mm-1);
              if (tst <= (eps2*fabsf(RD_D(mm)))*fabsf(RD_D(mm-1)) + safmin){ m2 = mm; break; }
            }
          }
          if (m2 > lend) WR_E(m2-1, 0.0f);
          float p = RD_D(l);
          if (m2 == l){
            WR_D(l, p); l = l - 1;
            if (l >= lend) continue;
            break;
          }
          if (m2 == l-1){
            float rt1, rt2, c1, s1;
            slaev2f(RD_D(l-1), RD_E(l-1), RD_D(l), &rt1, &rt2, &c1, &s1);
            WR_W(m2, c1); WR_W(3+m2, s1);
            ROTZ(l, c1, s1);
            WR_D(l-1, rt1); WR_D(l, rt2); WR_E(l-1, 0.0f);
            l = l - 2;
            if (l >= lend) continue;
            break;
          }
          if (jtot == nmaxit) break;
          jtot++;
          float g = (RD_D(l-1) - p) / (2.0f*RD_E(l-1));
          float r = slapy2f(g, 1.0f);
          g = RD_D(m2) - p + (RD_E(l-1) / (g + copysignf(r, g)));
          float s = 1.0f, c = 1.0f;
          p = 0.0f;
          for (int i = m2; i <= l-1; i++){
            float f  = s*RD_E(i);
            float bq = c*RD_E(i);
            slartgf(g, f, &c, &s, &r);
            if (i != m2) WR_E(i-1, r);
            g = RD_D(i) - p;
            r = (RD_D(i+1) - g)*s + (2.0f*c)*bq;
            p = s*r;
            WR_D(i, g + p);
            g = c*r - bq;
            WR_W(i, c);
            WR_W(3+i, s);
          }
          int mmn = l - m2 + 1;    // slasr('R','V','F')
          for (int j = 1; j <= mmn-1; j++){
            float ct = RD_W(m2+j-1), sx = RD_W(3+m2+j-1);
            if (ct != 1.0f || sx != 0.0f) ROTZ(m2+j, ct, sx);
          }
          WR_D(l, RD_D(l) - p);
          WR_E(l-1, g);
        }
      }
      if (jtot >= nmaxit) break;
    }
  }

  // argmin eigenvalue (first minimum — matches ssteqr selection-sort rank-0 pick)
  int kbest = 1;
  float dmin = d1;
  if (d2 < dmin){ dmin = d2; kbest = 2; }
  if (d3 < dmin){ dmin = d3; kbest = 3; }
  if (d4 < dmin){ dmin = d4; kbest = 4; }
  float zc1 = RD_Z(1,kbest);
  float zc2 = RD_Z(2,kbest);
  float zc3 = RD_Z(3,kbest);
  float zc4 = RD_Z(4,kbest);

  // sormtr: apply Q = H1*H2 (H2 first, then H1); H3 has tau=0
  {
    float v2 = A[4][2];
    float sum = zc3 + v2*zc4;
    float tt = tauv[2]*sum;
    zc3 = zc3 - tt;
    zc4 = zc4 - tt*v2;
  }
  {
    float va = A[3][1], vb = A[4][1];
    float sum = zc2 + va*zc3;
    sum = sum + vb*zc4;
    float tt = tauv[1]*sum;
    zc2 = zc2 - tt;
    zc3 = zc3 - tt*va;
    zc4 = zc4 - tt*vb;
  }

  // reference post-process: normalize by ||(a,b,c)||, sign-fix abc only
  float n2 = zc1*zc1;
  n2 = n2 + zc2*zc2;
  n2 = n2 + zc3*zc3;
  float nrm = sqrtf(n2);
  float a0 = zc1/nrm;
  float b0 = zc2/nrm;
  float c0 = zc3/nrm;
  float d0 = zc4/nrm;
  float sg = (b0 < 0.0f) ? -1.0f : 1.0f;
  a0 = a0*sg; b0 = b0*sg; c0 = c0*sg;

  if (threadIdx.x == 0){
    float* mp = &models[(size_t)t*4];
    mp[0]=a0; mp[1]=b0; mp[2]=c0; mp[3]=d0;
  }
}

// ---------------- Kernel 2: inlier counting (coalesced float4 LDS staging) ----------------
// Count arithmetic / order / atomics identical to R4 (bit-exact); only the path
// global->registers changed: float4 16B/lane coalesced into LDS, then stride-3
// float reads (gcd(3,32)=1 => bank-conflict-free).

__global__ void __launch_bounds__(256) count_kernel(const float* __restrict__ data,
                                                    const float* __restrict__ models,
                                                    int* __restrict__ counts){
  __shared__ float4 smodel[NIT];
  __shared__ float  s_pts[2048*3];     // 24 KB
  const int b = blockIdx.y;
  const int chunk = blockIdx.x;
  const int t = threadIdx.x;
  if (t < NIT) smodel[t] = ((const float4*)models)[t*BB + b];

  const float* src = data + ((long)b*NPTS + (long)chunk*2048)*3;
  #pragma unroll
  for (int j=0;j<6;j++)
    ((float4*)s_pts)[j*256 + t] = ((const float4*)src)[j*256 + t];
  __syncthreads();

  float x[8], y[8], z[8];
  #pragma unroll
  for (int k=0;k<8;k++){
    int p = 3*(k*256 + t);
    x[k]=s_pts[p]; y[k]=s_pts[p+1]; z[k]=s_pts[p+2];
  }
  const int lane = t & 63;
  for (int m=0;m<NIT;m++){
    float4 md = smodel[m];
    int cnt = 0;
    #pragma unroll
    for (int k=0;k<8;k++){
      // numpy einsum order, separate rounding (no FMA): ((a*x + b*y) + c*z) + d
      float s = __fmul_rn(md.x, x[k]);
      s = __fadd_rn(s, __fmul_rn(md.y, y[k]));
      s = __fadd_rn(s, __fmul_rn(md.z, z[k]));
      s = __fadd_rn(s, md.w);
      unsigned long long msk = __ballot(fabsf(s) < 0.05f);
      cnt += (int)__popcll(msk);
    }
    if (lane == 0) atomicAdd(&counts[m*BB + b], cnt);
  }
}

// ---------------- Kernel 3: parallel faithful scan + output (verbatim R4) ----------------

__global__ void __launch_bounds__(64) scan_kernel(const int* __restrict__ counts,
                                                  const float* __restrict__ models,
                                                  float* __restrict__ out){
  __shared__ int   icarr[NIT*BB];
  __shared__ int   pmarr[NIT*BB];
  __shared__ float karr[NIT*BB];
  __shared__ int   sdone[NIT];
  __shared__ int   sistop;
  const int lane = threadIdx.x;
  for (int t = lane; t < NIT*BB; t += 64) icarr[t] = counts[t];
  __syncthreads();
  if (lane < BB){
    int pm = 0;
    for (int it=0; it<NIT; it++){
      int ic = icarr[it*BB + lane];
      pm = (ic > pm) ? ic : pm;
      pmarr[it*BB + lane] = pm;
    }
  }
  __syncthreads();
  for (int t = lane; t < NIT*BB; t += 64){
    float p = (float)pmarr[t] / 32768.0f;
    float p3 = (p*p)*p;
    float prob = fminf(1.0f - p3, 0.99f);
    karr[t] = -0.35667494393873245f / (logf(prob) + 1e-10f);
  }
  __syncthreads();
  if (lane < NIT){
    float kmax = karr[lane*BB];
    for (int b=1;b<BB;b++) kmax = fmaxf(kmax, karr[lane*BB + b]);
    int reason = (int)kmax;            // astype(int32): trunc toward zero
    if (reason > 100) reason = 100;
    sdone[lane] = ((lane+1) >= reason) ? 1 : 0;
  }
  __syncthreads();
  if (lane == 0){
    int is = NIT-1;                    // guaranteed hit at it<=34 (reason<=35)
    for (int it=0; it<NIT; it++){ if (sdone[it]){ is = it; break; } }
    sistop = is;
  }
  __syncthreads();
  if (lane < BB){
    const int istop = sistop;
    int best = 0, bit = -1;
    for (int it=0; it<=istop; it++){
      int ic = icarr[it*BB + lane];
      if (ic > best){ best = ic; bit = it; }
    }
    float4 m = make_float4(0.0f,0.0f,0.0f,0.0f);
    if (bit >= 0) m = ((const float4*)models)[bit*BB + lane];
    ((float4*)out)[lane] = m;
  }
}

// ---------------- launch ----------------

extern "C" void kernel_launch(void* const* d_in, const int* in_sizes, int n_in,
                              void* d_out, int out_size, void* d_ws, size_t ws_size,
                              hipStream_t stream){
  const float* data = (const float*)d_in[0];
  const int*   idx  = (const int*)d_in[1];
  float* out = (float*)d_out;
  float* models = (float*)d_ws;                                        // NIT*32*4 floats
  int*   counts = (int*)((char*)d_ws + (size_t)NIT*BB*4*sizeof(float)); // NIT*32 ints

  models_kernel<<<NIT*BB, 64, 0, stream>>>(data, idx, models, counts);
  count_kernel<<<dim3(16, BB), 256, 0, stream>>>(data, models, counts);
  scan_kernel<<<1, 64, 0, stream>>>(counts, models, out);
}